// Round 7
// baseline (308.847 us; speedup 1.0000x reference)
//
#include <hip/hip_runtime.h>

#define HID 128
#define BN_EPS 1e-5f
#define CHUNK 8

typedef __attribute__((ext_vector_type(8))) short bf16x8;
typedef __attribute__((ext_vector_type(4))) float f32x4;

__device__ __forceinline__ float bf2f(unsigned short u) {
  union { unsigned int i; float f; } c; c.i = ((unsigned int)u) << 16; return c.f;
}
__device__ __forceinline__ unsigned short f2bf(float f) {
  union { float f; unsigned int i; } c; c.f = f;
  unsigned int u = c.i;
  return (unsigned short)((u + 0x7FFFu + ((u >> 16) & 1u)) >> 16);
}
__device__ __forceinline__ void unpack8(uint4 u, float* f) {
  f[0] = bf2f((unsigned short)(u.x & 0xffffu)); f[1] = bf2f((unsigned short)(u.x >> 16));
  f[2] = bf2f((unsigned short)(u.y & 0xffffu)); f[3] = bf2f((unsigned short)(u.y >> 16));
  f[4] = bf2f((unsigned short)(u.z & 0xffffu)); f[5] = bf2f((unsigned short)(u.z >> 16));
  f[6] = bf2f((unsigned short)(u.w & 0xffffu)); f[7] = bf2f((unsigned short)(u.w >> 16));
}
__device__ __forceinline__ uint4 pack8(const float* f) {
  uint4 u;
  u.x = (unsigned int)f2bf(f[0]) | ((unsigned int)f2bf(f[1]) << 16);
  u.y = (unsigned int)f2bf(f[2]) | ((unsigned int)f2bf(f[3]) << 16);
  u.z = (unsigned int)f2bf(f[4]) | ((unsigned int)f2bf(f[5]) << 16);
  u.w = (unsigned int)f2bf(f[6]) | ((unsigned int)f2bf(f[7]) << 16);
  return u;
}

// ---------------- degree histogram ------------------------------------------
__global__ __launch_bounds__(256) void k_hist(const int* __restrict__ src,
                                              const int* __restrict__ dst,
                                              int* deg, int E, int N) {
  const int stride = gridDim.x * blockDim.x;
  for (int i = blockIdx.x * blockDim.x + threadIdx.x; i < E; i += stride) {
    atomicAdd(&deg[src[i]], 1);
    atomicAdd(&deg[N + dst[i]], 1);
  }
}

__global__ __launch_bounds__(256) void k_norm(const int* __restrict__ deg,
                                              float* __restrict__ nsnd, int total) {
  int i = blockIdx.x * blockDim.x + threadIdx.x;
  if (i < total) nsnd[i] = rsqrtf(fmaxf((float)deg[i], 1.0f));
}

// ---------------- parallel scan ---------------------------------------------
__global__ __launch_bounds__(256) void k_scan_part(const int* __restrict__ deg,
                                                   int* __restrict__ bsum, int n) {
  __shared__ int red[256];
  const int t = threadIdx.x;
  const int i = blockIdx.x * 256 + t;
  red[t] = (i < n) ? deg[i] : 0;
  __syncthreads();
  for (int off = 128; off > 0; off >>= 1) {
    if (t < off) red[t] += red[t + off];
    __syncthreads();
  }
  if (t == 0) bsum[blockIdx.x] = red[0];
}

__global__ __launch_bounds__(1024) void k_scan_mid(int* bsum, int nb) {
  __shared__ int l[1024];
  const int t = threadIdx.x;
  l[t] = (t < nb) ? bsum[t] : 0;
  __syncthreads();
  for (int off = 1; off < 1024; off <<= 1) {
    int v = l[t];
    int add = (t >= off) ? l[t - off] : 0;
    __syncthreads();
    l[t] = v + add;
    __syncthreads();
  }
  if (t < nb) bsum[t] = (t == 0) ? 0 : l[t - 1];
}

__global__ __launch_bounds__(256) void k_scan_out(const int* __restrict__ deg,
                                                  const int* __restrict__ bpre,
                                                  int* __restrict__ offsets,
                                                  int* __restrict__ cursor, int n) {
  __shared__ int l[256];
  const int t = threadIdx.x;
  const int i = blockIdx.x * 256 + t;
  const int v = (i < n) ? deg[i] : 0;
  l[t] = v;
  __syncthreads();
  for (int off = 1; off < 256; off <<= 1) {
    int x = l[t];
    int add = (t >= off) ? l[t - off] : 0;
    __syncthreads();
    l[t] = x + add;
    __syncthreads();
  }
  const int excl = bpre[blockIdx.x] + l[t] - v;
  if (i < n) {
    offsets[i] = excl;
    cursor[i] = excl;
    if (i == n - 1) offsets[n] = excl + v;
  }
}

__global__ __launch_bounds__(256) void k_fill(const int* __restrict__ src,
                                              const int* __restrict__ dst,
                                              int* cursor, int* __restrict__ csc, int E) {
  const int stride = gridDim.x * blockDim.x;
  for (int i = blockIdx.x * blockDim.x + threadIdx.x; i < E; i += stride) {
    int d = dst[i];
    int pos = atomicAdd(&cursor[d], 1);
    csc[pos] = src[i];
  }
}

// ---------------- W (fp32 KxN row-major) -> Wt (bf16, [n][k]) ----------------
__global__ __launch_bounds__(256) void k_prep_w(const float* __restrict__ W,
                                                unsigned short* __restrict__ Wt) {
  int id = blockIdx.x * 256 + threadIdx.x;
  if (id < HID * HID) {
    int nn = id >> 7, kk = id & 127;
    Wt[id] = f2bf(W[kk * HID + nn]);
  }
}

// ---------------- per-feature BN params --------------------------------------
__global__ __launch_bounds__(128) void k_bnparams(const float* __restrict__ ST,
                                                  const float* __restrict__ gamma,
                                                  const float* __restrict__ beta,
                                                  float* __restrict__ PS,
                                                  float* __restrict__ PH, float invN) {
  const int t = threadIdx.x;
  float m = ST[t] * invN;
  float var = ST[HID + t] * invN - m * m;
  float sc = gamma[t] * rsqrtf(var + BN_EPS);
  PS[t] = sc;
  PH[t] = beta[t] - m * sc;
}

// ---------------- pre1: Xb = bf16( X * ns[row] )  (fp32 in) ------------------
__global__ __launch_bounds__(256) void k_pre1(const float* __restrict__ X,
                                              const float* __restrict__ ns,
                                              unsigned short* __restrict__ Xb, int nch) {
  const int stride = gridDim.x * 256;
  for (int ch = blockIdx.x * 256 + threadIdx.x; ch < nch; ch += stride) {
    const float sc = ns[ch >> 4];
    const float* p = X + (size_t)ch * 8;
    float4 v0 = *reinterpret_cast<const float4*>(p);
    float4 v1 = *reinterpret_cast<const float4*>(p + 4);
    float f[8] = {v0.x * sc, v0.y * sc, v0.z * sc, v0.w * sc,
                  v1.x * sc, v1.y * sc, v1.z * sc, v1.w * sc};
    *reinterpret_cast<uint4*>(Xb + (size_t)ch * 8) = pack8(f);
  }
}

// ---------------- pre2: Xb = bf16( prelu(H*PS+PH) * ns[row] ) (bf16 in) ------
__global__ __launch_bounds__(256) void k_pre2(const unsigned short* __restrict__ H,
                                              const float* __restrict__ PS,
                                              const float* __restrict__ PH,
                                              const float* __restrict__ aslope,
                                              const float* __restrict__ ns,
                                              unsigned short* __restrict__ Xb, int nch) {
  const float slope = aslope[0];
  const int stride = gridDim.x * 256;
  for (int ch = blockIdx.x * 256 + threadIdx.x; ch < nch; ch += stride) {
    const float sc = ns[ch >> 4];
    const int j0 = (ch & 15) * 8;
    uint4 u = *reinterpret_cast<const uint4*>(H + (size_t)ch * 8);
    float f[8];
    unpack8(u, f);
    float4 s0 = *reinterpret_cast<const float4*>(PS + j0);
    float4 s1 = *reinterpret_cast<const float4*>(PS + j0 + 4);
    float4 h0 = *reinterpret_cast<const float4*>(PH + j0);
    float4 h1 = *reinterpret_cast<const float4*>(PH + j0 + 4);
    float t;
    t = fmaf(f[0], s0.x, h0.x); f[0] = (t >= 0.f ? t : slope * t) * sc;
    t = fmaf(f[1], s0.y, h0.y); f[1] = (t >= 0.f ? t : slope * t) * sc;
    t = fmaf(f[2], s0.z, h0.z); f[2] = (t >= 0.f ? t : slope * t) * sc;
    t = fmaf(f[3], s0.w, h0.w); f[3] = (t >= 0.f ? t : slope * t) * sc;
    t = fmaf(f[4], s1.x, h1.x); f[4] = (t >= 0.f ? t : slope * t) * sc;
    t = fmaf(f[5], s1.y, h1.y); f[5] = (t >= 0.f ? t : slope * t) * sc;
    t = fmaf(f[6], s1.z, h1.z); f[6] = (t >= 0.f ? t : slope * t) * sc;
    t = fmaf(f[7], s1.w, h1.w); f[7] = (t >= 0.f ? t : slope * t) * sc;
    *reinterpret_cast<uint4*>(Xb + (size_t)ch * 8) = pack8(f);
  }
}

// ---------------- fused: Hout = bf16( nd * (A(Xb)) @ W + b ), + stats --------
// One wave per 16-row tile (N % 16 == 0). Agg: 2 rows at a time, 32 lanes/row,
// uint2/lane, CHUNK-deep prefetched gathers. Agg tile -> per-wave LDS (272B
// rows => 2-way bank conflicts only) -> MFMA A-frags. W in block LDS (same pad).
__global__ __launch_bounds__(256) void k_fused(const unsigned short* __restrict__ Xb,
                                               const unsigned short* __restrict__ Wt,
                                               const int* __restrict__ offsets,
                                               const int* __restrict__ csc,
                                               const float* __restrict__ nd,
                                               const float* __restrict__ bias,
                                               unsigned short* __restrict__ Hout,
                                               float* stats, int ntiles) {
  __shared__ __align__(16) unsigned short Wl[HID * 136];     // 34.8 KB
  __shared__ __align__(16) unsigned short Al[4][16 * 136];   // 4 x 4.35 KB
  __shared__ float reds[HID], redq[HID];
  const int tid = threadIdx.x;

  // cooperative W stage: 16384 shorts = 256 threads x 8 uint4
#pragma unroll
  for (int u = 0; u < 8; ++u) {
    int sidx = (tid * 8 + u) * 8;
    int nn = sidx >> 7, kk = sidx & 127;
    *reinterpret_cast<uint4*>(reinterpret_cast<char*>(Wl) + nn * 272 + kk * 2) =
        *reinterpret_cast<const uint4*>(Wt + nn * HID + kk);
  }
  if (tid < HID) reds[tid] = 0.f; else redq[tid - HID] = 0.f;
  __syncthreads();

  const int wib = tid >> 6;
  const int lane = tid & 63;
  const int c = lane & 15, g = lane >> 4;   // MFMA frag coords
  const int rl = lane >> 5, fl = lane & 31; // agg coords: 2 rows x 32 lanes
  char* Aw = reinterpret_cast<char*>(Al[wib]);
  float s[8]   = {0.f, 0.f, 0.f, 0.f, 0.f, 0.f, 0.f, 0.f};
  float sqv[8] = {0.f, 0.f, 0.f, 0.f, 0.f, 0.f, 0.f, 0.f};

  const int t_idx = blockIdx.x * 4 + wib;
  if (t_idx < ntiles) {
    const int row0 = t_idx * 16;
    // ---- aggregate 16 rows (2 per pass) ----
    for (int p = 0; p < 8; ++p) {
      const int i = row0 + p * 2 + rl;
      const int e0 = offsets[i], e1 = offsets[i + 1];
      float acc[4] = {0.f, 0.f, 0.f, 0.f};
      for (int e = e0; e < e1; e += CHUNK) {
        int idx[CHUNK];
#pragma unroll
        for (int k = 0; k < CHUNK; ++k) idx[k] = csc[min(e + k, e1 - 1)];
        uint2 v[CHUNK];
#pragma unroll
        for (int k = 0; k < CHUNK; ++k)
          v[k] = *reinterpret_cast<const uint2*>(Xb + (size_t)idx[k] * HID + fl * 4);
#pragma unroll
        for (int k = 0; k < CHUNK; ++k) {
          if (e + k < e1) {
            acc[0] += bf2f((unsigned short)(v[k].x & 0xffffu));
            acc[1] += bf2f((unsigned short)(v[k].x >> 16));
            acc[2] += bf2f((unsigned short)(v[k].y & 0xffffu));
            acc[3] += bf2f((unsigned short)(v[k].y >> 16));
          }
        }
      }
      uint2 pk;
      pk.x = (unsigned int)f2bf(acc[0]) | ((unsigned int)f2bf(acc[1]) << 16);
      pk.y = (unsigned int)f2bf(acc[2]) | ((unsigned int)f2bf(acc[3]) << 16);
      *reinterpret_cast<uint2*>(Aw + (p * 2 + rl) * 272 + fl * 8) = pk;
    }
    asm volatile("" ::: "memory");  // order LDS writes before frag reads

    // ---- MFMA: A (aggregated tile) x W ----
    bf16x8 afr[4];
#pragma unroll
    for (int kt = 0; kt < 4; ++kt)
      afr[kt] = *reinterpret_cast<const bf16x8*>(Aw + c * 272 + (kt * 32 + g * 8) * 2);
    f32x4 acc[8];
#pragma unroll
    for (int ct = 0; ct < 8; ++ct) acc[ct] = (f32x4){0.f, 0.f, 0.f, 0.f};
#pragma unroll
    for (int kt = 0; kt < 4; ++kt)
#pragma unroll
      for (int ct = 0; ct < 8; ++ct) {
        bf16x8 bfr = *reinterpret_cast<const bf16x8*>(
            reinterpret_cast<char*>(Wl) + (ct * 16 + c) * 272 + (kt * 32 + g * 8) * 2);
        acc[ct] = __builtin_amdgcn_mfma_f32_16x16x32_bf16(afr[kt], bfr, acc[ct], 0, 0, 0);
      }
    asm volatile("" ::: "memory");  // afr reads done before Al reuse

    // ---- epilogue: *nd + bias, stats, repack to LDS, coalesced store ----
    float ndq[4];
#pragma unroll
    for (int q = 0; q < 4; ++q) ndq[q] = nd[row0 + g * 4 + q];
#pragma unroll
    for (int ct = 0; ct < 8; ++ct) {
      const float bj = bias[ct * 16 + c];
#pragma unroll
      for (int q = 0; q < 4; ++q) {
        float val = acc[ct][q] * ndq[q] + bj;
        s[ct] += val;
        sqv[ct] += val * val;
        *reinterpret_cast<unsigned short*>(Aw + (g * 4 + q) * 272 + (ct * 16 + c) * 2) =
            f2bf(val);
      }
    }
    asm volatile("" ::: "memory");
#pragma unroll
    for (int p2 = 0; p2 < 4; ++p2) {
      const int rloc = p2 * 4 + g;
      uint4 vv = *reinterpret_cast<const uint4*>(Aw + rloc * 272 + c * 16);
      *reinterpret_cast<uint4*>(Hout + (size_t)(row0 + rloc) * HID + c * 8) = vv;
    }
#pragma unroll
    for (int ct = 0; ct < 8; ++ct) {
      atomicAdd(&reds[ct * 16 + c], s[ct]);
      atomicAdd(&redq[ct * 16 + c], sqv[ct]);
    }
  }
  __syncthreads();
  if (tid < HID) atomicAdd(&stats[tid], reds[tid]);
  else atomicAdd(&stats[HID + (tid - HID)], redq[tid - HID]);
}

// ---------------- final BN + PReLU (bf16 in, fp32 out) -----------------------
__global__ __launch_bounds__(256) void k_bn_final(const unsigned short* __restrict__ IN,
                                                  float* __restrict__ OUT,
                                                  const float* __restrict__ PS,
                                                  const float* __restrict__ PH,
                                                  const float* __restrict__ a, int total4) {
  const float slope = a[0];
  const int stride = gridDim.x * blockDim.x;
  for (int i = blockIdx.x * blockDim.x + threadIdx.x; i < total4; i += stride) {
    int j4 = i & 31;
    float4 ps = reinterpret_cast<const float4*>(PS)[j4];
    float4 ph = reinterpret_cast<const float4*>(PH)[j4];
    uint2 u = *reinterpret_cast<const uint2*>(IN + (size_t)i * 4);
    float4 o;
    float t;
    t = fmaf(bf2f((unsigned short)(u.x & 0xffffu)), ps.x, ph.x); o.x = t >= 0.f ? t : slope * t;
    t = fmaf(bf2f((unsigned short)(u.x >> 16)),     ps.y, ph.y); o.y = t >= 0.f ? t : slope * t;
    t = fmaf(bf2f((unsigned short)(u.y & 0xffffu)), ps.z, ph.z); o.z = t >= 0.f ? t : slope * t;
    t = fmaf(bf2f((unsigned short)(u.y >> 16)),     ps.w, ph.w); o.w = t >= 0.f ? t : slope * t;
    reinterpret_cast<float4*>(OUT)[i] = o;
  }
}

extern "C" void kernel_launch(void* const* d_in, const int* in_sizes, int n_in,
                              void* d_out, int out_size, void* d_ws, size_t ws_size,
                              hipStream_t stream) {
  const float* X   = (const float*)d_in[0];
  const float* W1  = (const float*)d_in[1];
  const float* b1  = (const float*)d_in[2];
  const float* g1  = (const float*)d_in[3];
  const float* be1 = (const float*)d_in[4];
  const float* a1  = (const float*)d_in[5];
  const float* W2  = (const float*)d_in[6];
  const float* b2  = (const float*)d_in[7];
  const float* g2  = (const float*)d_in[8];
  const float* be2 = (const float*)d_in[9];
  const float* a2  = (const float*)d_in[10];
  const int*   ei  = (const int*)d_in[11];

  const int N = in_sizes[0] / HID;
  const int E = in_sizes[11] / 2;
  const int* src = ei;
  const int* dst = ei + E;

  float* out = (float*)d_out;

  // workspace layout (4-byte units)
  unsigned short* bufX = (unsigned short*)d_ws;            // N*128 bf16 (agg input)
  unsigned short* bufH = bufX + (size_t)N * HID;           // N*128 bf16 (layer out)
  int*   deg     = (int*)(bufH + (size_t)N * HID);         // 2N ints
  float* NSND    = (float*)(deg + 2 * (size_t)N);          // 2N floats (NS then ND)
  float* ST      = NSND + 2 * (size_t)N;                   // 512 floats
  int*   offsets = (int*)(ST + 512);                       // N+1
  int*   csc     = offsets + N + 1;                        // E
  int*   bsum    = csc + E;                                // <=1024
  unsigned short* Wt1 = (unsigned short*)(bsum + 1024);    // 128*128 bf16
  unsigned short* Wt2 = Wt1 + HID * HID;                   // 128*128 bf16
  float* PS1 = (float*)(Wt2 + HID * HID);
  float* PH1 = PS1 + HID;
  float* PS2 = PH1 + HID;
  float* PH2 = PS2 + HID;
  int*   cursor  = deg;                                    // alias out-deg

  const float invN = 1.0f / (float)N;
  const int nb = (N + 255) / 256;
  const int ntiles = (N + 15) / 16;       // N=50000 -> 3125, exact
  const int fgrid = (ntiles + 3) / 4;     // 4 waves (tiles) per block
  const int nch = N * (HID / 8);

  hipMemsetAsync(deg, 0, 2 * (size_t)N * sizeof(int), stream);
  hipMemsetAsync(ST, 0, 512 * sizeof(float), stream);

  // graph preprocessing + weight prep (once)
  k_hist<<<1024, 256, 0, stream>>>(src, dst, deg, E, N);
  k_norm<<<(2 * N + 255) / 256, 256, 0, stream>>>(deg, NSND, 2 * N);
  k_scan_part<<<nb, 256, 0, stream>>>(deg + N, bsum, N);
  k_scan_mid<<<1, 1024, 0, stream>>>(bsum, nb);
  k_scan_out<<<nb, 256, 0, stream>>>(deg + N, bsum, offsets, cursor, N);
  k_fill<<<1024, 256, 0, stream>>>(src, dst, cursor, csc, E);
  k_prep_w<<<(HID * HID + 255) / 256, 256, 0, stream>>>(W1, Wt1);
  k_prep_w<<<(HID * HID + 255) / 256, 256, 0, stream>>>(W2, Wt2);

  // ---- layer 1: agg-first (linearity: nd*(A(x*ns))@W + b) ----
  k_pre1<<<2048, 256, 0, stream>>>(X, NSND, bufX, nch);
  k_fused<<<fgrid, 256, 0, stream>>>(bufX, Wt1, offsets, csc, NSND + N, b1, bufH, ST, ntiles);
  k_bnparams<<<1, 128, 0, stream>>>(ST, g1, be1, PS1, PH1, invN);

  // ---- layer 2 ----
  k_pre2<<<2048, 256, 0, stream>>>(bufH, PS1, PH1, a1, NSND, bufX, nch);
  k_fused<<<fgrid, 256, 0, stream>>>(bufX, Wt2, offsets, csc, NSND + N, b2, bufH, ST + 256, ntiles);
  k_bnparams<<<1, 128, 0, stream>>>(ST + 256, g2, be2, PS2, PH2, invN);
  k_bn_final<<<2048, 256, 0, stream>>>(bufH, out, PS2, PH2, a2, N * (HID / 4));
}

// Round 8
// 301.224 us; speedup vs baseline: 1.0253x; 1.0253x over previous
//
#include <hip/hip_runtime.h>

#define HID 128
#define BN_EPS 1e-5f
#define CHUNK 8

typedef __attribute__((ext_vector_type(8))) short bf16x8;
typedef __attribute__((ext_vector_type(4))) float f32x4;

__device__ __forceinline__ float bf2f(unsigned short u) {
  union { unsigned int i; float f; } c; c.i = ((unsigned int)u) << 16; return c.f;
}
__device__ __forceinline__ unsigned short f2bf(float f) {
  union { float f; unsigned int i; } c; c.f = f;
  unsigned int u = c.i;
  return (unsigned short)((u + 0x7FFFu + ((u >> 16) & 1u)) >> 16);
}
__device__ __forceinline__ void unpack8(uint4 u, float* f) {
  f[0] = bf2f((unsigned short)(u.x & 0xffffu)); f[1] = bf2f((unsigned short)(u.x >> 16));
  f[2] = bf2f((unsigned short)(u.y & 0xffffu)); f[3] = bf2f((unsigned short)(u.y >> 16));
  f[4] = bf2f((unsigned short)(u.z & 0xffffu)); f[5] = bf2f((unsigned short)(u.z >> 16));
  f[6] = bf2f((unsigned short)(u.w & 0xffffu)); f[7] = bf2f((unsigned short)(u.w >> 16));
}

// ---------------- degree histogram ------------------------------------------
__global__ __launch_bounds__(256) void k_hist(const int* __restrict__ src,
                                              const int* __restrict__ dst,
                                              int* deg, int E, int N) {
  const int stride = gridDim.x * blockDim.x;
  for (int i = blockIdx.x * blockDim.x + threadIdx.x; i < E; i += stride) {
    atomicAdd(&deg[src[i]], 1);
    atomicAdd(&deg[N + dst[i]], 1);
  }
}

__global__ __launch_bounds__(256) void k_norm(const int* __restrict__ deg,
                                              float* __restrict__ nsnd, int total) {
  int i = blockIdx.x * blockDim.x + threadIdx.x;
  if (i < total) nsnd[i] = rsqrtf(fmaxf((float)deg[i], 1.0f));
}

// ---------------- parallel scan ---------------------------------------------
__global__ __launch_bounds__(256) void k_scan_part(const int* __restrict__ deg,
                                                   int* __restrict__ bsum, int n) {
  __shared__ int red[256];
  const int t = threadIdx.x;
  const int i = blockIdx.x * 256 + t;
  red[t] = (i < n) ? deg[i] : 0;
  __syncthreads();
  for (int off = 128; off > 0; off >>= 1) {
    if (t < off) red[t] += red[t + off];
    __syncthreads();
  }
  if (t == 0) bsum[blockIdx.x] = red[0];
}

__global__ __launch_bounds__(1024) void k_scan_mid(int* bsum, int nb) {
  __shared__ int l[1024];
  const int t = threadIdx.x;
  l[t] = (t < nb) ? bsum[t] : 0;
  __syncthreads();
  for (int off = 1; off < 1024; off <<= 1) {
    int v = l[t];
    int add = (t >= off) ? l[t - off] : 0;
    __syncthreads();
    l[t] = v + add;
    __syncthreads();
  }
  if (t < nb) bsum[t] = (t == 0) ? 0 : l[t - 1];
}

__global__ __launch_bounds__(256) void k_scan_out(const int* __restrict__ deg,
                                                  const int* __restrict__ bpre,
                                                  int* __restrict__ offsets,
                                                  int* __restrict__ cursor, int n) {
  __shared__ int l[256];
  const int t = threadIdx.x;
  const int i = blockIdx.x * 256 + t;
  const int v = (i < n) ? deg[i] : 0;
  l[t] = v;
  __syncthreads();
  for (int off = 1; off < 256; off <<= 1) {
    int x = l[t];
    int add = (t >= off) ? l[t - off] : 0;
    __syncthreads();
    l[t] = x + add;
    __syncthreads();
  }
  const int excl = bpre[blockIdx.x] + l[t] - v;
  if (i < n) {
    offsets[i] = excl;
    cursor[i] = excl;
    if (i == n - 1) offsets[n] = excl + v;
  }
}

__global__ __launch_bounds__(256) void k_fill(const int* __restrict__ src,
                                              const int* __restrict__ dst,
                                              int* cursor, int* __restrict__ csc, int E) {
  const int stride = gridDim.x * blockDim.x;
  for (int i = blockIdx.x * blockDim.x + threadIdx.x; i < E; i += stride) {
    int d = dst[i];
    int pos = atomicAdd(&cursor[d], 1);
    csc[pos] = src[i];
  }
}

// ---------------- W (fp32 KxN row-major) -> Wt (bf16, [n][k]) ----------------
__global__ __launch_bounds__(256) void k_prep_w(const float* __restrict__ W,
                                                unsigned short* __restrict__ Wt) {
  int id = blockIdx.x * 256 + threadIdx.x;
  if (id < HID * HID) {
    int nn = id >> 7, kk = id & 127;
    Wt[id] = f2bf(W[kk * HID + nn]);
  }
}

// ---------------- per-feature BN params --------------------------------------
__global__ __launch_bounds__(128) void k_bnparams(const float* __restrict__ ST,
                                                  const float* __restrict__ gamma,
                                                  const float* __restrict__ beta,
                                                  float* __restrict__ PS,
                                                  float* __restrict__ PH, float invN) {
  const int t = threadIdx.x;
  float m = ST[t] * invN;
  float var = ST[HID + t] * invN - m * m;
  float sc = gamma[t] * rsqrtf(var + BN_EPS);
  PS[t] = sc;
  PH[t] = beta[t] - m * sc;
}

// ---------------- MFMA GEMM: Gb[row,:] = bf16( A[row,:] @ W ) ----------------
// MODE 0: A = fp32 X * ns[row].  MODE 1: A = prelu(bf16 X * PS + PH) * ns[row].
// One wave per 16-row block, grid-stride; W frags resident in VGPRs.
template <int MODE>
__global__ __launch_bounds__(256) void k_gemm_mfma(const void* __restrict__ Xin,
                                                   const unsigned short* __restrict__ Wt,
                                                   const float* __restrict__ ns,
                                                   const float* __restrict__ PS,
                                                   const float* __restrict__ PH,
                                                   const float* __restrict__ aslope,
                                                   unsigned short* __restrict__ Gb, int n) {
  __shared__ __align__(16) unsigned short stile[4][16 * 136];
  const int wib = threadIdx.x >> 6;
  const int lane = threadIdx.x & 63;
  const int c = lane & 15;
  const int g = lane >> 4;
  const int nrb = (n + 15) >> 4;
  const int nw = gridDim.x * 4;

  bf16x8 bfr[8][4];
#pragma unroll
  for (int ct = 0; ct < 8; ++ct)
#pragma unroll
    for (int kt = 0; kt < 4; ++kt)
      bfr[ct][kt] = *reinterpret_cast<const bf16x8*>(Wt + (ct * 16 + c) * HID + kt * 32 + g * 8);

  const float slope = (MODE == 1) ? aslope[0] : 0.f;

  for (int w = blockIdx.x * 4 + wib; w < nrb; w += nw) {
    const int row0 = w * 16;
    int arow = row0 + c;
    if (arow > n - 1) arow = n - 1;
    const float sc = ns[arow];
    bf16x8 afr[4];
    if (MODE == 0) {
      const float* X = (const float*)Xin;
#pragma unroll
      for (int kt = 0; kt < 4; ++kt) {
        const float* p = X + (size_t)arow * HID + kt * 32 + g * 8;
        float4 v0 = *reinterpret_cast<const float4*>(p);
        float4 v1 = *reinterpret_cast<const float4*>(p + 4);
        bf16x8 a;
        a[0] = (short)f2bf(v0.x * sc); a[1] = (short)f2bf(v0.y * sc);
        a[2] = (short)f2bf(v0.z * sc); a[3] = (short)f2bf(v0.w * sc);
        a[4] = (short)f2bf(v1.x * sc); a[5] = (short)f2bf(v1.y * sc);
        a[6] = (short)f2bf(v1.z * sc); a[7] = (short)f2bf(v1.w * sc);
        afr[kt] = a;
      }
    } else {
      const unsigned short* Xb = (const unsigned short*)Xin;
#pragma unroll
      for (int kt = 0; kt < 4; ++kt) {
        const int k0 = kt * 32 + g * 8;
        uint4 u = *reinterpret_cast<const uint4*>(Xb + (size_t)arow * HID + k0);
        float f[8];
        unpack8(u, f);
        float4 s0 = *reinterpret_cast<const float4*>(PS + k0);
        float4 s1 = *reinterpret_cast<const float4*>(PS + k0 + 4);
        float4 h0 = *reinterpret_cast<const float4*>(PH + k0);
        float4 h1 = *reinterpret_cast<const float4*>(PH + k0 + 4);
        float t;
        t = fmaf(f[0], s0.x, h0.x); f[0] = (t >= 0.f ? t : slope * t) * sc;
        t = fmaf(f[1], s0.y, h0.y); f[1] = (t >= 0.f ? t : slope * t) * sc;
        t = fmaf(f[2], s0.z, h0.z); f[2] = (t >= 0.f ? t : slope * t) * sc;
        t = fmaf(f[3], s0.w, h0.w); f[3] = (t >= 0.f ? t : slope * t) * sc;
        t = fmaf(f[4], s1.x, h1.x); f[4] = (t >= 0.f ? t : slope * t) * sc;
        t = fmaf(f[5], s1.y, h1.y); f[5] = (t >= 0.f ? t : slope * t) * sc;
        t = fmaf(f[6], s1.z, h1.z); f[6] = (t >= 0.f ? t : slope * t) * sc;
        t = fmaf(f[7], s1.w, h1.w); f[7] = (t >= 0.f ? t : slope * t) * sc;
        bf16x8 a;
        a[0] = (short)f2bf(f[0]); a[1] = (short)f2bf(f[1]);
        a[2] = (short)f2bf(f[2]); a[3] = (short)f2bf(f[3]);
        a[4] = (short)f2bf(f[4]); a[5] = (short)f2bf(f[5]);
        a[6] = (short)f2bf(f[6]); a[7] = (short)f2bf(f[7]);
        afr[kt] = a;
      }
    }

    f32x4 acc[8];
#pragma unroll
    for (int ct = 0; ct < 8; ++ct) acc[ct] = (f32x4){0.f, 0.f, 0.f, 0.f};
#pragma unroll
    for (int kt = 0; kt < 4; ++kt)
#pragma unroll
      for (int ct = 0; ct < 8; ++ct)
        acc[ct] = __builtin_amdgcn_mfma_f32_16x16x32_bf16(afr[kt], bfr[ct][kt], acc[ct], 0, 0, 0);

    // C layout: col = lane&15, row = (lane>>4)*4 + q  (per-wave LDS tile repack)
#pragma unroll
    for (int ct = 0; ct < 8; ++ct)
#pragma unroll
      for (int q = 0; q < 4; ++q)
        stile[wib][(g * 4 + q) * 136 + ct * 16 + c] = f2bf(acc[ct][q]);

#pragma unroll
    for (int p = 0; p < 4; ++p) {
      int rl = p * 4 + g;
      int grow = row0 + rl;
      if (grow < n) {
        uint4 v = *reinterpret_cast<const uint4*>(&stile[wib][rl * 136 + c * 8]);
        *reinterpret_cast<uint4*>(Gb + (size_t)grow * HID + c * 8) = v;
      }
    }
  }
}

// ---------------- gather-aggregate (bf16 in/out) + stats ---------------------
// R5-proven geometry: 32 lanes/row (uint2), 8 row-slots per 256-block.
__global__ __launch_bounds__(256) void k_agg_finish(const unsigned short* __restrict__ H,
                                                    const int* __restrict__ offsets,
                                                    const int* __restrict__ csc,
                                                    const float* __restrict__ nd,
                                                    const float* __restrict__ bias,
                                                    unsigned short* __restrict__ OUT,
                                                    float* stats, int n) {
  const int lane = threadIdx.x & 31;  // features 4*lane .. 4*lane+3
  const int slot = threadIdx.x >> 5;  // 8 row-slots per block
  const int rstride = gridDim.x * 8;
  const float4 bj = reinterpret_cast<const float4*>(bias)[lane];
  float4 s = {0.f, 0.f, 0.f, 0.f}, sq = {0.f, 0.f, 0.f, 0.f};

  for (int i = blockIdx.x * 8 + slot; i < n; i += rstride) {
    const int e0 = offsets[i];
    const int e1 = offsets[i + 1];
    float4 acc = {0.f, 0.f, 0.f, 0.f};
    for (int e = e0; e < e1; e += CHUNK) {
      int idx[CHUNK];
#pragma unroll
      for (int k = 0; k < CHUNK; ++k) idx[k] = csc[min(e + k, e1 - 1)];
      uint2 v[CHUNK];
#pragma unroll
      for (int k = 0; k < CHUNK; ++k)
        v[k] = *reinterpret_cast<const uint2*>(H + (size_t)idx[k] * HID + lane * 4);
#pragma unroll
      for (int k = 0; k < CHUNK; ++k) {
        if (e + k < e1) {
          acc.x += bf2f((unsigned short)(v[k].x & 0xffffu));
          acc.y += bf2f((unsigned short)(v[k].x >> 16));
          acc.z += bf2f((unsigned short)(v[k].y & 0xffffu));
          acc.w += bf2f((unsigned short)(v[k].y >> 16));
        }
      }
    }
    const float ndv = nd[i];
    float4 o;
    o.x = acc.x * ndv + bj.x;
    o.y = acc.y * ndv + bj.y;
    o.z = acc.z * ndv + bj.z;
    o.w = acc.w * ndv + bj.w;
    uint2 pk;
    pk.x = (unsigned int)f2bf(o.x) | ((unsigned int)f2bf(o.y) << 16);
    pk.y = (unsigned int)f2bf(o.z) | ((unsigned int)f2bf(o.w) << 16);
    *reinterpret_cast<uint2*>(OUT + (size_t)i * HID + lane * 4) = pk;
    s.x += o.x; s.y += o.y; s.z += o.z; s.w += o.w;
    sq.x += o.x * o.x; sq.y += o.y * o.y; sq.z += o.z * o.z; sq.w += o.w * o.w;
  }

  __shared__ float red[2][8][HID];  // 8 KB, conflict-free
  *reinterpret_cast<float4*>(&red[0][slot][lane * 4]) = s;
  *reinterpret_cast<float4*>(&red[1][slot][lane * 4]) = sq;
  __syncthreads();
  const int t = threadIdx.x;
  if (t < HID) {
    float a = 0.f;
#pragma unroll
    for (int k = 0; k < 8; ++k) a += red[0][k][t];
    atomicAdd(&stats[t], a);
  } else {
    const int j = t - HID;
    float a = 0.f;
#pragma unroll
    for (int k = 0; k < 8; ++k) a += red[1][k][j];
    atomicAdd(&stats[HID + j], a);
  }
}

// ---------------- final BN + PReLU (bf16 in, fp32 out) -----------------------
__global__ __launch_bounds__(256) void k_bn_final(const unsigned short* __restrict__ IN,
                                                  float* __restrict__ OUT,
                                                  const float* __restrict__ PS,
                                                  const float* __restrict__ PH,
                                                  const float* __restrict__ a, int total4) {
  const float slope = a[0];
  const int stride = gridDim.x * blockDim.x;
  for (int i = blockIdx.x * blockDim.x + threadIdx.x; i < total4; i += stride) {
    int j4 = i & 31;
    float4 ps = reinterpret_cast<const float4*>(PS)[j4];
    float4 ph = reinterpret_cast<const float4*>(PH)[j4];
    uint2 u = *reinterpret_cast<const uint2*>(IN + (size_t)i * 4);
    float4 o;
    float t;
    t = fmaf(bf2f((unsigned short)(u.x & 0xffffu)), ps.x, ph.x); o.x = t >= 0.f ? t : slope * t;
    t = fmaf(bf2f((unsigned short)(u.x >> 16)),     ps.y, ph.y); o.y = t >= 0.f ? t : slope * t;
    t = fmaf(bf2f((unsigned short)(u.y & 0xffffu)), ps.z, ph.z); o.z = t >= 0.f ? t : slope * t;
    t = fmaf(bf2f((unsigned short)(u.y >> 16)),     ps.w, ph.w); o.w = t >= 0.f ? t : slope * t;
    reinterpret_cast<float4*>(OUT)[i] = o;
  }
}

extern "C" void kernel_launch(void* const* d_in, const int* in_sizes, int n_in,
                              void* d_out, int out_size, void* d_ws, size_t ws_size,
                              hipStream_t stream) {
  const float* X   = (const float*)d_in[0];
  const float* W1  = (const float*)d_in[1];
  const float* b1  = (const float*)d_in[2];
  const float* g1  = (const float*)d_in[3];
  const float* be1 = (const float*)d_in[4];
  const float* a1  = (const float*)d_in[5];
  const float* W2  = (const float*)d_in[6];
  const float* b2  = (const float*)d_in[7];
  const float* g2  = (const float*)d_in[8];
  const float* be2 = (const float*)d_in[9];
  const float* a2  = (const float*)d_in[10];
  const int*   ei  = (const int*)d_in[11];

  const int N = in_sizes[0] / HID;
  const int E = in_sizes[11] / 2;
  const int* src = ei;
  const int* dst = ei + E;

  float* out = (float*)d_out;

  // workspace layout
  unsigned short* bufA = (unsigned short*)d_ws;            // N*128 bf16
  unsigned short* bufB = bufA + (size_t)N * HID;           // N*128 bf16
  int*   deg     = (int*)(bufB + (size_t)N * HID);         // 2N ints
  float* NSND    = (float*)(deg + 2 * (size_t)N);          // 2N floats (NS then ND)
  float* ST      = NSND + 2 * (size_t)N;                   // 512 floats (2 layers)
  int*   offsets = (int*)(ST + 512);                       // N+1
  int*   csc     = offsets + N + 1;                        // E
  int*   bsum    = csc + E;                                // <=1024
  unsigned short* Wt1 = (unsigned short*)(bsum + 1024);    // 128*128 bf16
  unsigned short* Wt2 = Wt1 + HID * HID;                   // 128*128 bf16
  float* PS1 = (float*)(Wt2 + HID * HID);                  // 128
  float* PH1 = PS1 + HID;                                  // 128
  float* PS2 = PH1 + HID;                                  // 128
  float* PH2 = PS2 + HID;                                  // 128
  int*   cursor  = deg;                                    // alias out-deg

  const float invN = 1.0f / (float)N;
  const int nb = (N + 255) / 256;

  hipMemsetAsync(deg, 0, 2 * (size_t)N * sizeof(int), stream);
  hipMemsetAsync(ST, 0, 512 * sizeof(float), stream);

  // graph preprocessing + weight prep (once)
  k_hist<<<1024, 256, 0, stream>>>(src, dst, deg, E, N);
  k_norm<<<(2 * N + 255) / 256, 256, 0, stream>>>(deg, NSND, 2 * N);
  k_scan_part<<<nb, 256, 0, stream>>>(deg + N, bsum, N);
  k_scan_mid<<<1, 1024, 0, stream>>>(bsum, nb);
  k_scan_out<<<nb, 256, 0, stream>>>(deg + N, bsum, offsets, cursor, N);
  k_fill<<<1024, 256, 0, stream>>>(src, dst, cursor, csc, E);
  k_prep_w<<<(HID * HID + 255) / 256, 256, 0, stream>>>(W1, Wt1);
  k_prep_w<<<(HID * HID + 255) / 256, 256, 0, stream>>>(W2, Wt2);

  // ---- layer 1 ----
  k_gemm_mfma<0><<<512, 256, 0, stream>>>(X, Wt1, NSND, nullptr, nullptr, nullptr, bufA, N);
  k_agg_finish<<<2048, 256, 0, stream>>>(bufA, offsets, csc, NSND + N, b1, bufB, ST, N);
  k_bnparams<<<1, 128, 0, stream>>>(ST, g1, be1, PS1, PH1, invN);

  // ---- layer 2 (BN1+PReLU1+ns fused into GEMM A-path) ----
  k_gemm_mfma<1><<<512, 256, 0, stream>>>(bufB, Wt2, NSND, PS1, PH1, a1, bufA, N);
  k_agg_finish<<<2048, 256, 0, stream>>>(bufA, offsets, csc, NSND + N, b2, bufB, ST + 256, N);
  k_bnparams<<<1, 128, 0, stream>>>(ST + 256, g2, be2, PS2, PH2, invN);
  k_bn_final<<<2048, 256, 0, stream>>>(bufB, out, PS2, PH2, a2, N * (HID / 4));
}

// Round 9
// 248.745 us; speedup vs baseline: 1.2416x; 1.2110x over previous
//
#include <hip/hip_runtime.h>

#define HID 128
#define BN_EPS 1e-5f
#define CHUNK 8

typedef __attribute__((ext_vector_type(8))) short bf16x8;
typedef __attribute__((ext_vector_type(4))) float f32x4;

__device__ __forceinline__ float bf2f(unsigned short u) {
  union { unsigned int i; float f; } c; c.i = ((unsigned int)u) << 16; return c.f;
}
__device__ __forceinline__ unsigned short f2bf(float f) {
  union { float f; unsigned int i; } c; c.f = f;
  unsigned int u = c.i;
  return (unsigned short)((u + 0x7FFFu + ((u >> 16) & 1u)) >> 16);
}
__device__ __forceinline__ void unpack8(uint4 u, float* f) {
  f[0] = bf2f((unsigned short)(u.x & 0xffffu)); f[1] = bf2f((unsigned short)(u.x >> 16));
  f[2] = bf2f((unsigned short)(u.y & 0xffffu)); f[3] = bf2f((unsigned short)(u.y >> 16));
  f[4] = bf2f((unsigned short)(u.z & 0xffffu)); f[5] = bf2f((unsigned short)(u.z >> 16));
  f[6] = bf2f((unsigned short)(u.w & 0xffffu)); f[7] = bf2f((unsigned short)(u.w >> 16));
}

// ---------------- degree histogram ------------------------------------------
__global__ __launch_bounds__(256) void k_hist(const int* __restrict__ src,
                                              const int* __restrict__ dst,
                                              int* deg, int E, int N) {
  const int stride = gridDim.x * blockDim.x;
  for (int i = blockIdx.x * blockDim.x + threadIdx.x; i < E; i += stride) {
    atomicAdd(&deg[src[i]], 1);
    atomicAdd(&deg[N + dst[i]], 1);
  }
}

__global__ __launch_bounds__(256) void k_norm(const int* __restrict__ deg,
                                              float* __restrict__ nsnd, int total) {
  int i = blockIdx.x * blockDim.x + threadIdx.x;
  if (i < total) nsnd[i] = rsqrtf(fmaxf((float)deg[i], 1.0f));
}

// ---------------- parallel scan ---------------------------------------------
__global__ __launch_bounds__(256) void k_scan_part(const int* __restrict__ deg,
                                                   int* __restrict__ bsum, int n) {
  __shared__ int red[256];
  const int t = threadIdx.x;
  const int i = blockIdx.x * 256 + t;
  red[t] = (i < n) ? deg[i] : 0;
  __syncthreads();
  for (int off = 128; off > 0; off >>= 1) {
    if (t < off) red[t] += red[t + off];
    __syncthreads();
  }
  if (t == 0) bsum[blockIdx.x] = red[0];
}

__global__ __launch_bounds__(1024) void k_scan_mid(int* bsum, int nb) {
  __shared__ int l[1024];
  const int t = threadIdx.x;
  l[t] = (t < nb) ? bsum[t] : 0;
  __syncthreads();
  for (int off = 1; off < 1024; off <<= 1) {
    int v = l[t];
    int add = (t >= off) ? l[t - off] : 0;
    __syncthreads();
    l[t] = v + add;
    __syncthreads();
  }
  if (t < nb) bsum[t] = (t == 0) ? 0 : l[t - 1];
}

__global__ __launch_bounds__(256) void k_scan_out(const int* __restrict__ deg,
                                                  const int* __restrict__ bpre,
                                                  int* __restrict__ offsets,
                                                  int* __restrict__ cursor, int n) {
  __shared__ int l[256];
  const int t = threadIdx.x;
  const int i = blockIdx.x * 256 + t;
  const int v = (i < n) ? deg[i] : 0;
  l[t] = v;
  __syncthreads();
  for (int off = 1; off < 256; off <<= 1) {
    int x = l[t];
    int add = (t >= off) ? l[t - off] : 0;
    __syncthreads();
    l[t] = x + add;
    __syncthreads();
  }
  const int excl = bpre[blockIdx.x] + l[t] - v;
  if (i < n) {
    offsets[i] = excl;
    cursor[i] = excl;
    if (i == n - 1) offsets[n] = excl + v;
  }
}

__global__ __launch_bounds__(256) void k_fill(const int* __restrict__ src,
                                              const int* __restrict__ dst,
                                              int* cursor, int* __restrict__ csc, int E) {
  const int stride = gridDim.x * blockDim.x;
  for (int i = blockIdx.x * blockDim.x + threadIdx.x; i < E; i += stride) {
    int d = dst[i];
    int pos = atomicAdd(&cursor[d], 1);
    csc[pos] = src[i];
  }
}

// ---------------- W (fp32 KxN row-major) -> Wt (bf16, [n][k]) ----------------
__global__ __launch_bounds__(256) void k_prep_w(const float* __restrict__ W,
                                                unsigned short* __restrict__ Wt) {
  int id = blockIdx.x * 256 + threadIdx.x;
  if (id < HID * HID) {
    int nn = id >> 7, kk = id & 127;
    Wt[id] = f2bf(W[kk * HID + nn]);
  }
}

// ---------------- per-feature BN params --------------------------------------
__global__ __launch_bounds__(128) void k_bnparams(const float* __restrict__ ST,
                                                  const float* __restrict__ gamma,
                                                  const float* __restrict__ beta,
                                                  float* __restrict__ PS,
                                                  float* __restrict__ PH, float invN) {
  const int t = threadIdx.x;
  float m = ST[t] * invN;
  float var = ST[HID + t] * invN - m * m;
  float sc = gamma[t] * rsqrtf(var + BN_EPS);
  PS[t] = sc;
  PH[t] = beta[t] - m * sc;
}

// ---------------- MFMA GEMM: Gb[row,:] = bf16( A[row,:] @ W ) ----------------
// MODE 0: A = fp32 X * ns[row].  MODE 1: A = prelu(bf16 X * PS + PH) * ns[row].
template <int MODE>
__global__ __launch_bounds__(256) void k_gemm_mfma(const void* __restrict__ Xin,
                                                   const unsigned short* __restrict__ Wt,
                                                   const float* __restrict__ ns,
                                                   const float* __restrict__ PS,
                                                   const float* __restrict__ PH,
                                                   const float* __restrict__ aslope,
                                                   unsigned short* __restrict__ Gb, int n) {
  __shared__ __align__(16) unsigned short stile[4][16 * 136];
  const int wib = threadIdx.x >> 6;
  const int lane = threadIdx.x & 63;
  const int c = lane & 15;
  const int g = lane >> 4;
  const int nrb = (n + 15) >> 4;
  const int nw = gridDim.x * 4;

  bf16x8 bfr[8][4];
#pragma unroll
  for (int ct = 0; ct < 8; ++ct)
#pragma unroll
    for (int kt = 0; kt < 4; ++kt)
      bfr[ct][kt] = *reinterpret_cast<const bf16x8*>(Wt + (ct * 16 + c) * HID + kt * 32 + g * 8);

  const float slope = (MODE == 1) ? aslope[0] : 0.f;

  for (int w = blockIdx.x * 4 + wib; w < nrb; w += nw) {
    const int row0 = w * 16;
    int arow = row0 + c;
    if (arow > n - 1) arow = n - 1;
    const float sc = ns[arow];
    bf16x8 afr[4];
    if (MODE == 0) {
      const float* X = (const float*)Xin;
#pragma unroll
      for (int kt = 0; kt < 4; ++kt) {
        const float* p = X + (size_t)arow * HID + kt * 32 + g * 8;
        float4 v0 = *reinterpret_cast<const float4*>(p);
        float4 v1 = *reinterpret_cast<const float4*>(p + 4);
        bf16x8 a;
        a[0] = (short)f2bf(v0.x * sc); a[1] = (short)f2bf(v0.y * sc);
        a[2] = (short)f2bf(v0.z * sc); a[3] = (short)f2bf(v0.w * sc);
        a[4] = (short)f2bf(v1.x * sc); a[5] = (short)f2bf(v1.y * sc);
        a[6] = (short)f2bf(v1.z * sc); a[7] = (short)f2bf(v1.w * sc);
        afr[kt] = a;
      }
    } else {
      const unsigned short* Xb = (const unsigned short*)Xin;
#pragma unroll
      for (int kt = 0; kt < 4; ++kt) {
        const int k0 = kt * 32 + g * 8;
        uint4 u = *reinterpret_cast<const uint4*>(Xb + (size_t)arow * HID + k0);
        float f[8];
        unpack8(u, f);
        float4 s0 = *reinterpret_cast<const float4*>(PS + k0);
        float4 s1 = *reinterpret_cast<const float4*>(PS + k0 + 4);
        float4 h0 = *reinterpret_cast<const float4*>(PH + k0);
        float4 h1 = *reinterpret_cast<const float4*>(PH + k0 + 4);
        float t;
        t = fmaf(f[0], s0.x, h0.x); f[0] = (t >= 0.f ? t : slope * t) * sc;
        t = fmaf(f[1], s0.y, h0.y); f[1] = (t >= 0.f ? t : slope * t) * sc;
        t = fmaf(f[2], s0.z, h0.z); f[2] = (t >= 0.f ? t : slope * t) * sc;
        t = fmaf(f[3], s0.w, h0.w); f[3] = (t >= 0.f ? t : slope * t) * sc;
        t = fmaf(f[4], s1.x, h1.x); f[4] = (t >= 0.f ? t : slope * t) * sc;
        t = fmaf(f[5], s1.y, h1.y); f[5] = (t >= 0.f ? t : slope * t) * sc;
        t = fmaf(f[6], s1.z, h1.z); f[6] = (t >= 0.f ? t : slope * t) * sc;
        t = fmaf(f[7], s1.w, h1.w); f[7] = (t >= 0.f ? t : slope * t) * sc;
        bf16x8 a;
        a[0] = (short)f2bf(f[0]); a[1] = (short)f2bf(f[1]);
        a[2] = (short)f2bf(f[2]); a[3] = (short)f2bf(f[3]);
        a[4] = (short)f2bf(f[4]); a[5] = (short)f2bf(f[5]);
        a[6] = (short)f2bf(f[6]); a[7] = (short)f2bf(f[7]);
        afr[kt] = a;
      }
    }

    f32x4 acc[8];
#pragma unroll
    for (int ct = 0; ct < 8; ++ct) acc[ct] = (f32x4){0.f, 0.f, 0.f, 0.f};
#pragma unroll
    for (int kt = 0; kt < 4; ++kt)
#pragma unroll
      for (int ct = 0; ct < 8; ++ct)
        acc[ct] = __builtin_amdgcn_mfma_f32_16x16x32_bf16(afr[kt], bfr[ct][kt], acc[ct], 0, 0, 0);

#pragma unroll
    for (int ct = 0; ct < 8; ++ct)
#pragma unroll
      for (int q = 0; q < 4; ++q)
        stile[wib][(g * 4 + q) * 136 + ct * 16 + c] = f2bf(acc[ct][q]);

#pragma unroll
    for (int p = 0; p < 4; ++p) {
      int rl = p * 4 + g;
      int grow = row0 + rl;
      if (grow < n) {
        uint4 v = *reinterpret_cast<const uint4*>(&stile[wib][rl * 136 + c * 8]);
        *reinterpret_cast<uint4*>(Gb + (size_t)grow * HID + c * 8) = v;
      }
    }
  }
}

// ---------------- gather-aggregate (bf16 in/out) + stats ---------------------
// 32 lanes/row (uint2), 8 slots/block, TWO independent rows per slot (2x MLP).
// Grid 1024 (measured optimum: more blocks = fabric contention, R8).
__global__ __launch_bounds__(256) void k_agg_finish(const unsigned short* __restrict__ H,
                                                    const int* __restrict__ offsets,
                                                    const int* __restrict__ csc,
                                                    const float* __restrict__ nd,
                                                    const float* __restrict__ bias,
                                                    unsigned short* __restrict__ OUT,
                                                    float* stats, int n) {
  const int lane = threadIdx.x & 31;  // features 4*lane .. 4*lane+3
  const int slot = threadIdx.x >> 5;  // 8 slots/block, each owns row pair (i, i+1)
  const int rstride = gridDim.x * 16;
  const float4 bj = reinterpret_cast<const float4*>(bias)[lane];
  float4 s = {0.f, 0.f, 0.f, 0.f}, sq = {0.f, 0.f, 0.f, 0.f};

  for (int i0 = blockIdx.x * 16 + slot * 2; i0 < n; i0 += rstride) {
    const int iA = i0, iB = i0 + 1;  // n even -> iB always valid
    const int eA0 = offsets[iA], eA1 = offsets[iA + 1];
    const int eB0 = offsets[iB], eB1 = offsets[iB + 1];
    const int lenA = eA1 - eA0, lenB = eB1 - eB0;
    const int maxlen = max(lenA, lenB);
    float4 accA = {0.f, 0.f, 0.f, 0.f}, accB = {0.f, 0.f, 0.f, 0.f};
    for (int e = 0; e < maxlen; e += CHUNK) {
      int idxA[CHUNK], idxB[CHUNK];
#pragma unroll
      for (int k = 0; k < CHUNK; ++k) {
        idxA[k] = csc[max(min(eA0 + e + k, eA1 - 1), 0)];
        idxB[k] = csc[max(min(eB0 + e + k, eB1 - 1), 0)];
      }
      uint2 vA[CHUNK], vB[CHUNK];
#pragma unroll
      for (int k = 0; k < CHUNK; ++k) {
        vA[k] = *reinterpret_cast<const uint2*>(H + (size_t)idxA[k] * HID + lane * 4);
        vB[k] = *reinterpret_cast<const uint2*>(H + (size_t)idxB[k] * HID + lane * 4);
      }
#pragma unroll
      for (int k = 0; k < CHUNK; ++k) {
        if (e + k < lenA) {
          accA.x += bf2f((unsigned short)(vA[k].x & 0xffffu));
          accA.y += bf2f((unsigned short)(vA[k].x >> 16));
          accA.z += bf2f((unsigned short)(vA[k].y & 0xffffu));
          accA.w += bf2f((unsigned short)(vA[k].y >> 16));
        }
        if (e + k < lenB) {
          accB.x += bf2f((unsigned short)(vB[k].x & 0xffffu));
          accB.y += bf2f((unsigned short)(vB[k].x >> 16));
          accB.z += bf2f((unsigned short)(vB[k].y & 0xffffu));
          accB.w += bf2f((unsigned short)(vB[k].y >> 16));
        }
      }
    }
    const float ndA = nd[iA], ndB = nd[iB];
    float4 oA, oB;
    oA.x = accA.x * ndA + bj.x; oA.y = accA.y * ndA + bj.y;
    oA.z = accA.z * ndA + bj.z; oA.w = accA.w * ndA + bj.w;
    oB.x = accB.x * ndB + bj.x; oB.y = accB.y * ndB + bj.y;
    oB.z = accB.z * ndB + bj.z; oB.w = accB.w * ndB + bj.w;
    uint2 pkA, pkB;
    pkA.x = (unsigned int)f2bf(oA.x) | ((unsigned int)f2bf(oA.y) << 16);
    pkA.y = (unsigned int)f2bf(oA.z) | ((unsigned int)f2bf(oA.w) << 16);
    pkB.x = (unsigned int)f2bf(oB.x) | ((unsigned int)f2bf(oB.y) << 16);
    pkB.y = (unsigned int)f2bf(oB.z) | ((unsigned int)f2bf(oB.w) << 16);
    *reinterpret_cast<uint2*>(OUT + (size_t)iA * HID + lane * 4) = pkA;
    *reinterpret_cast<uint2*>(OUT + (size_t)iB * HID + lane * 4) = pkB;
    s.x += oA.x + oB.x; s.y += oA.y + oB.y;
    s.z += oA.z + oB.z; s.w += oA.w + oB.w;
    sq.x += oA.x * oA.x + oB.x * oB.x; sq.y += oA.y * oA.y + oB.y * oB.y;
    sq.z += oA.z * oA.z + oB.z * oB.z; sq.w += oA.w * oA.w + oB.w * oB.w;
  }

  __shared__ float red[2][8][HID];  // 8 KB, conflict-free
  *reinterpret_cast<float4*>(&red[0][slot][lane * 4]) = s;
  *reinterpret_cast<float4*>(&red[1][slot][lane * 4]) = sq;
  __syncthreads();
  const int t = threadIdx.x;
  if (t < HID) {
    float a = 0.f;
#pragma unroll
    for (int k = 0; k < 8; ++k) a += red[0][k][t];
    atomicAdd(&stats[t], a);
  } else {
    const int j = t - HID;
    float a = 0.f;
#pragma unroll
    for (int k = 0; k < 8; ++k) a += red[1][k][j];
    atomicAdd(&stats[HID + j], a);
  }
}

// ---------------- final BN + PReLU (bf16 in, fp32 out) -----------------------
__global__ __launch_bounds__(256) void k_bn_final(const unsigned short* __restrict__ IN,
                                                  float* __restrict__ OUT,
                                                  const float* __restrict__ PS,
                                                  const float* __restrict__ PH,
                                                  const float* __restrict__ a, int total4) {
  const float slope = a[0];
  const int stride = gridDim.x * blockDim.x;
  for (int i = blockIdx.x * blockDim.x + threadIdx.x; i < total4; i += stride) {
    int j4 = i & 31;
    float4 ps = reinterpret_cast<const float4*>(PS)[j4];
    float4 ph = reinterpret_cast<const float4*>(PH)[j4];
    uint2 u = *reinterpret_cast<const uint2*>(IN + (size_t)i * 4);
    float4 o;
    float t;
    t = fmaf(bf2f((unsigned short)(u.x & 0xffffu)), ps.x, ph.x); o.x = t >= 0.f ? t : slope * t;
    t = fmaf(bf2f((unsigned short)(u.x >> 16)),     ps.y, ph.y); o.y = t >= 0.f ? t : slope * t;
    t = fmaf(bf2f((unsigned short)(u.y & 0xffffu)), ps.z, ph.z); o.z = t >= 0.f ? t : slope * t;
    t = fmaf(bf2f((unsigned short)(u.y >> 16)),     ps.w, ph.w); o.w = t >= 0.f ? t : slope * t;
    reinterpret_cast<float4*>(OUT)[i] = o;
  }
}

extern "C" void kernel_launch(void* const* d_in, const int* in_sizes, int n_in,
                              void* d_out, int out_size, void* d_ws, size_t ws_size,
                              hipStream_t stream) {
  const float* X   = (const float*)d_in[0];
  const float* W1  = (const float*)d_in[1];
  const float* b1  = (const float*)d_in[2];
  const float* g1  = (const float*)d_in[3];
  const float* be1 = (const float*)d_in[4];
  const float* a1  = (const float*)d_in[5];
  const float* W2  = (const float*)d_in[6];
  const float* b2  = (const float*)d_in[7];
  const float* g2  = (const float*)d_in[8];
  const float* be2 = (const float*)d_in[9];
  const float* a2  = (const float*)d_in[10];
  const int*   ei  = (const int*)d_in[11];

  const int N = in_sizes[0] / HID;
  const int E = in_sizes[11] / 2;
  const int* src = ei;
  const int* dst = ei + E;

  float* out = (float*)d_out;

  // workspace layout
  unsigned short* bufA = (unsigned short*)d_ws;            // N*128 bf16
  unsigned short* bufB = bufA + (size_t)N * HID;           // N*128 bf16
  int*   deg     = (int*)(bufB + (size_t)N * HID);         // 2N ints
  float* NSND    = (float*)(deg + 2 * (size_t)N);          // 2N floats (NS then ND)
  float* ST      = NSND + 2 * (size_t)N;                   // 512 floats (2 layers)
  int*   offsets = (int*)(ST + 512);                       // N+1
  int*   csc     = offsets + N + 1;                        // E
  int*   bsum    = csc + E;                                // <=1024
  unsigned short* Wt1 = (unsigned short*)(bsum + 1024);    // 128*128 bf16
  unsigned short* Wt2 = Wt1 + HID * HID;                   // 128*128 bf16
  float* PS1 = (float*)(Wt2 + HID * HID);                  // 128
  float* PH1 = PS1 + HID;                                  // 128
  float* PS2 = PH1 + HID;                                  // 128
  float* PH2 = PS2 + HID;                                  // 128
  int*   cursor  = deg;                                    // alias out-deg

  const float invN = 1.0f / (float)N;
  const int nb = (N + 255) / 256;

  hipMemsetAsync(deg, 0, 2 * (size_t)N * sizeof(int), stream);
  hipMemsetAsync(ST, 0, 512 * sizeof(float), stream);

  // graph preprocessing + weight prep (once)
  k_hist<<<1024, 256, 0, stream>>>(src, dst, deg, E, N);
  k_norm<<<(2 * N + 255) / 256, 256, 0, stream>>>(deg, NSND, 2 * N);
  k_scan_part<<<nb, 256, 0, stream>>>(deg + N, bsum, N);
  k_scan_mid<<<1, 1024, 0, stream>>>(bsum, nb);
  k_scan_out<<<nb, 256, 0, stream>>>(deg + N, bsum, offsets, cursor, N);
  k_fill<<<1024, 256, 0, stream>>>(src, dst, cursor, csc, E);
  k_prep_w<<<(HID * HID + 255) / 256, 256, 0, stream>>>(W1, Wt1);
  k_prep_w<<<(HID * HID + 255) / 256, 256, 0, stream>>>(W2, Wt2);

  // ---- layer 1 ----
  k_gemm_mfma<0><<<512, 256, 0, stream>>>(X, Wt1, NSND, nullptr, nullptr, nullptr, bufA, N);
  k_agg_finish<<<1024, 256, 0, stream>>>(bufA, offsets, csc, NSND + N, b1, bufB, ST, N);
  k_bnparams<<<1, 128, 0, stream>>>(ST, g1, be1, PS1, PH1, invN);

  // ---- layer 2 (BN1+PReLU1+ns fused into GEMM A-path) ----
  k_gemm_mfma<1><<<512, 256, 0, stream>>>(bufB, Wt2, NSND, PS1, PH1, a1, bufA, N);
  k_agg_finish<<<1024, 256, 0, stream>>>(bufA, offsets, csc, NSND + N, b2, bufB, ST + 256, N);
  k_bnparams<<<1, 128, 0, stream>>>(ST + 256, g2, be2, PS2, PH2, invN);
  k_bn_final<<<2048, 256, 0, stream>>>(bufB, out, PS2, PH2, a2, N * (HID / 4));
}